// Round 6
// baseline (213.721 us; speedup 1.0000x reference)
//
#include <hip/hip_runtime.h>
#include <stdint.h>

#define S_LEN 4096
#define D_DIM 64
#define KBLK  64
#define QBLK  64

typedef __attribute__((ext_vector_type(8))) short bf16x8;
typedef __attribute__((ext_vector_type(4))) float f32x4;

__device__ __forceinline__ uint32_t f2bf(float f) {
    uint32_t u = __float_as_uint(f);
    return (u + 0x7FFFu + ((u >> 16) & 1u)) >> 16;
}
__device__ __forceinline__ uint32_t pack2bf(float lo, float hi) {
    return f2bf(lo) | (f2bf(hi) << 16);
}
__device__ __forceinline__ uint32_t rotl32(uint32_t x, int n) {
    return (x << n) | (x >> (32 - n));
}

// JAX partitionable threefry 32-bit draw, key (0,42), flat index idx < 2^32.
// Plaintext (x0,x1) = (counts_hi, counts_lo) = (0, idx).
// Under x64-off, uint64 iota canonicalizes to uint32, so the 32-bit narrow
// cannot be "build 64b then truncate": draw = out0 ^ out1 (XOR fold).
// Hypothesis ladder: r4 out0 ✗, r5 out1 ✗, r6 (this) out0^out1.
__device__ __forceinline__ uint32_t threefry_xor(uint32_t idx) {
    const uint32_t k0 = 0u, k1 = 42u;
    const uint32_t k2 = 0x1BD11BDAu ^ k0 ^ k1;   // 0x1BD11BF0
    uint32_t x0 = k0;            // counts_hi (=0) + ks[0]
    uint32_t x1 = idx + k1;      // counts_lo (=idx) + ks[1]
#define TFR(r) { x0 += x1; x1 = rotl32(x1, (r)); x1 ^= x0; }
    TFR(13) TFR(15) TFR(26) TFR(6)
    x0 += k1; x1 += k2 + 1u;
    TFR(17) TFR(29) TFR(16) TFR(24)
    x0 += k2; x1 += k0 + 2u;
    TFR(13) TFR(15) TFR(26) TFR(6)
    x0 += k0; x1 += k1 + 3u;
    TFR(17) TFR(29) TFR(16) TFR(24)
    x0 += k1; x1 += k2 + 4u;
    TFR(13) TFR(15) TFR(26) TFR(6)
    x0 += k2; x1 += k0 + 5u;     // both outputs fully keyed
#undef TFR
    return x0 ^ x1;
}

// keep  <=>  uniform(bits) < 0.8f  <=>  bits < 0xCCCCCE00  (exact)
#define KEEP_THRESH 0xCCCCCE00u

// Flash attention + JAX-threefry(partitionable, xor-fold) dropout.
// Block: 256 threads (4 waves). Wave w owns q-rows [blockIdx.x*64 + w*16, +16).
// Swapped QK^T: S^T = mfma(K_frag, Q_frag); C layout col=lane&15 (q), row=4*(lane>>4)+reg (k).
__global__ void attn_dropout_kernel(const float* __restrict__ Qp,
                                    const float* __restrict__ Kp,
                                    const float* __restrict__ Vp,
                                    const int* __restrict__ isf,
                                    float* __restrict__ Op) {
    const int tid  = threadIdx.x;
    const int w    = tid >> 6;
    const int lane = tid & 63;
    const int g    = lane >> 4;   // 16-lane group 0..3
    const int lq   = lane & 15;   // q-column / n index
    const int b    = blockIdx.y;
    const int qwave = blockIdx.x * QBLK + w * 16;

    __shared__ __align__(16) unsigned char smem[24576];
    unsigned char* Kl = smem;              // K tile  bf16 [64][64], row stride 128B, swizzled
    unsigned char* Vt = smem + 8192;       // V^T     bf16 [d=64][k=64], swizzled
    unsigned char* Pl = smem + 16384 + w * 2048;  // per-wave P bf16 [16 q][64 k], swizzled

    // robust scale read: int32 expected; fall back to f32 bit pattern if insane
    float fv;
    {
        int iv = isf[0];
        if (iv >= 1 && iv <= (1 << 20)) fv = (float)iv;
        else {
            float f = __int_as_float(iv);
            fv = (f > 1.0e-3f && f < 1.0e6f) ? f : 8.0f;
        }
    }
    const float sc = 1.0f / fv;

    // ---- Q fragments (B-operand of swapped QK): lane holds Q[qwave+lq][32h+8g+j]*sc
    bf16x8 qf[2];
    {
        const float* qp = Qp + (size_t)(b * S_LEN + qwave + lq) * D_DIM + 8 * g;
        #pragma unroll
        for (int h = 0; h < 2; ++h) {
            float4 a = *(const float4*)(qp + 32 * h);
            float4 c = *(const float4*)(qp + 32 * h + 4);
            bf16x8 f;
            f[0] = (short)f2bf(a.x * sc); f[1] = (short)f2bf(a.y * sc);
            f[2] = (short)f2bf(a.z * sc); f[3] = (short)f2bf(a.w * sc);
            f[4] = (short)f2bf(c.x * sc); f[5] = (short)f2bf(c.y * sc);
            f[6] = (short)f2bf(c.z * sc); f[7] = (short)f2bf(c.w * sc);
            qf[h] = f;
        }
    }

    f32x4 acc[4];
    #pragma unroll
    for (int nt = 0; nt < 4; ++nt) { acc[nt][0]=0.f; acc[nt][1]=0.f; acc[nt][2]=0.f; acc[nt][3]=0.f; }
    float mrun = -3.0e38f, lrun = 0.0f;

    const float* Kb = Kp + (size_t)b * S_LEN * D_DIM;
    const float* Vb = Vp + (size_t)b * S_LEN * D_DIM;

    for (int kt = 0; kt < S_LEN / KBLK; ++kt) {
        const int kbase = kt * KBLK;
        __syncthreads();   // previous iter's LDS reads done before overwrite

        // ---- stage K tile (bf16, swizzled ^((row&7)<<4))
        #pragma unroll
        for (int i = 0; i < 4; ++i) {
            int p4 = i * 256 + tid;            // float4 index in 64x16
            int r  = p4 >> 4, c4 = p4 & 15;
            float4 v = *(const float4*)(Kb + (size_t)(kbase + r) * D_DIM + c4 * 4);
            uint2 wv; wv.x = pack2bf(v.x, v.y); wv.y = pack2bf(v.z, v.w);
            *(uint2*)(Kl + ((r * 128 + c4 * 8) ^ ((r & 7) << 4))) = wv;
        }
        // ---- stage V^T (bf16): pack k-pairs so writes are u32
        #pragma unroll
        for (int i = 0; i < 2; ++i) {
            int pp = i * 256 + tid;            // pair index 0..511
            int kp = pp >> 4, d4 = (pp & 15) * 4;
            const float* vp = Vb + (size_t)(kbase + 2 * kp) * D_DIM + d4;
            float4 a = *(const float4*)vp;
            float4 c = *(const float4*)(vp + D_DIM);
            *(uint32_t*)(Vt + (((d4 + 0) * 128 + kp * 4) ^ (((d4 + 0) & 7) << 4))) = pack2bf(a.x, c.x);
            *(uint32_t*)(Vt + (((d4 + 1) * 128 + kp * 4) ^ (((d4 + 1) & 7) << 4))) = pack2bf(a.y, c.y);
            *(uint32_t*)(Vt + (((d4 + 2) * 128 + kp * 4) ^ (((d4 + 2) & 7) << 4))) = pack2bf(a.z, c.z);
            *(uint32_t*)(Vt + (((d4 + 3) * 128 + kp * 4) ^ (((d4 + 3) & 7) << 4))) = pack2bf(a.w, c.w);
        }
        __syncthreads();

        // ---- S^T = K_tile @ Q^T  (4 m-tiles of 16 k-positions, K-dim 64 = 2 halves)
        f32x4 s[4];
        #pragma unroll
        for (int mt = 0; mt < 4; ++mt) { s[mt][0]=0.f; s[mt][1]=0.f; s[mt][2]=0.f; s[mt][3]=0.f; }
        #pragma unroll
        for (int h = 0; h < 2; ++h) {
            #pragma unroll
            for (int mt = 0; mt < 4; ++mt) {
                int r = 16 * mt + lq;
                bf16x8 kf = *(const bf16x8*)(Kl + ((r * 128 + (4 * h + g) * 16) ^ ((r & 7) << 4)));
                s[mt] = __builtin_amdgcn_mfma_f32_16x16x32_bf16(kf, qf[h], s[mt], 0, 0, 0);
            }
        }

        // ---- online softmax over k for column q = qwave+lq (lane-parallel, reduce over groups)
        float tmax = s[0][0];
        #pragma unroll
        for (int mt = 0; mt < 4; ++mt)
            #pragma unroll
            for (int r = 0; r < 4; ++r) tmax = fmaxf(tmax, s[mt][r]);
        tmax = fmaxf(tmax, __shfl_xor(tmax, 16));
        tmax = fmaxf(tmax, __shfl_xor(tmax, 32));
        float mnew = fmaxf(mrun, tmax);
        float pvv[4][4];
        float tsum = 0.f;
        #pragma unroll
        for (int mt = 0; mt < 4; ++mt)
            #pragma unroll
            for (int r = 0; r < 4; ++r) {
                float e = __expf(s[mt][r] - mnew);
                pvv[mt][r] = e; tsum += e;
            }
        tsum += __shfl_xor(tsum, 16);
        tsum += __shfl_xor(tsum, 32);
        float corr = __expf(mrun - mnew);
        lrun = lrun * corr + tsum;   // denominator: pre-dropout
        mrun = mnew;

        // ---- dropout: JAX partitionable threefry (xor-fold), flat idx = b*2^24 + q*2^12 + k
        const uint32_t cbase = ((uint32_t)b << 24) + ((uint32_t)(qwave + lq) << 12) + (uint32_t)kbase;
        #pragma unroll
        for (int mt = 0; mt < 4; ++mt) {
            float pd[4];
            #pragma unroll
            for (int r = 0; r < 4; ++r) {
                uint32_t bits = threefry_xor(cbase + (uint32_t)(16 * mt + 4 * g + r));
                pd[r] = (bits < KEEP_THRESH) ? pvv[mt][r] : 0.0f;  // 1/0.8 folded into epilogue
            }
            uint2 pw; pw.x = pack2bf(pd[0], pd[1]); pw.y = pack2bf(pd[2], pd[3]);
            *(uint2*)(Pl + ((lq * 128 + (16 * mt + 4 * g) * 2) ^ ((lq & 7) << 4))) = pw;
        }

        // Compiler memory fence: P written via uint2*, read via bf16x8*, no barrier
        // between (per-wave buffer). Prevents TBAA-based reordering; HW DS ops are
        // in-order per wave so a compiler-only fence suffices.
        asm volatile("" ::: "memory");

        // ---- rescale O accumulator (rows q' = 4g+r need corr from lane q')
        float cr0 = __shfl(corr, 4 * g + 0);
        float cr1 = __shfl(corr, 4 * g + 1);
        float cr2 = __shfl(corr, 4 * g + 2);
        float cr3 = __shfl(corr, 4 * g + 3);
        #pragma unroll
        for (int nt = 0; nt < 4; ++nt) {
            acc[nt][0] *= cr0; acc[nt][1] *= cr1; acc[nt][2] *= cr2; acc[nt][3] *= cr3;
        }

        // ---- PV: O += P @ V   (A = P from LDS, B = V^T rows from LDS)
        #pragma unroll
        for (int kk = 0; kk < 2; ++kk) {
            bf16x8 pf = *(const bf16x8*)(Pl + ((lq * 128 + kk * 64 + g * 16) ^ ((lq & 7) << 4)));
            #pragma unroll
            for (int nt = 0; nt < 4; ++nt) {
                int d = lq + 16 * nt;
                bf16x8 vf = *(const bf16x8*)(Vt + ((d * 128 + kk * 64 + g * 16) ^ ((d & 7) << 4)));
                acc[nt] = __builtin_amdgcn_mfma_f32_16x16x32_bf16(pf, vf, acc[nt], 0, 0, 0);
            }
        }
    }

    // ---- epilogue: O = acc / (l * 0.8)
    float l0 = __shfl(lrun, 4 * g + 0);
    float l1 = __shfl(lrun, 4 * g + 1);
    float l2 = __shfl(lrun, 4 * g + 2);
    float l3 = __shfl(lrun, 4 * g + 3);
    float inv0 = 1.0f / (l0 * 0.8f);
    float inv1 = 1.0f / (l1 * 0.8f);
    float inv2 = 1.0f / (l2 * 0.8f);
    float inv3 = 1.0f / (l3 * 0.8f);
    float* Ob = Op + (size_t)b * S_LEN * D_DIM;
    #pragma unroll
    for (int nt = 0; nt < 4; ++nt) {
        int d = lq + 16 * nt;
        Ob[(size_t)(qwave + 4 * g + 0) * D_DIM + d] = acc[nt][0] * inv0;
        Ob[(size_t)(qwave + 4 * g + 1) * D_DIM + d] = acc[nt][1] * inv1;
        Ob[(size_t)(qwave + 4 * g + 2) * D_DIM + d] = acc[nt][2] * inv2;
        Ob[(size_t)(qwave + 4 * g + 3) * D_DIM + d] = acc[nt][3] * inv3;
    }
}

extern "C" void kernel_launch(void* const* d_in, const int* in_sizes, int n_in,
                              void* d_out, int out_size, void* d_ws, size_t ws_size,
                              hipStream_t stream) {
    const float* Q = (const float*)d_in[0];
    const float* K = (const float*)d_in[1];
    const float* V = (const float*)d_in[2];
    const int* isf = (const int*)d_in[3];
    float* O = (float*)d_out;
    dim3 grid(S_LEN / QBLK, 4);
    attn_dropout_kernel<<<grid, dim3(256), 0, stream>>>(Q, K, V, isf, O);
}

// Round 8
// 172.211 us; speedup vs baseline: 1.2410x; 1.2410x over previous
//
#include <hip/hip_runtime.h>
#include <stdint.h>

#define S_LEN 4096
#define D_DIM 64
#define KBLK  64
#define QBLK  64
#define NBATCH 4
#define ROWSTRIDE 66   // per-row ws floats: [m, l, O[64]]

typedef __attribute__((ext_vector_type(8))) short bf16x8;
typedef __attribute__((ext_vector_type(4))) float f32x4;

__device__ __forceinline__ uint32_t f2bf(float f) {
    uint32_t u = __float_as_uint(f);
    return (u + 0x7FFFu + ((u >> 16) & 1u)) >> 16;
}
__device__ __forceinline__ uint32_t pack2bf(float lo, float hi) {
    return f2bf(lo) | (f2bf(hi) << 16);
}
__device__ __forceinline__ uint32_t rotl32(uint32_t x, int n) {
    return (x << n) | (x >> (32 - n));   // lowered to v_alignbit_b32
}

// JAX partitionable threefry 32-bit draw, key (0,42): plaintext (0, idx),
// draw = out0 ^ out1. Verified round 6 (absmax 1.46e-3).
__device__ __forceinline__ uint32_t threefry_xor(uint32_t idx) {
    const uint32_t k0 = 0u, k1 = 42u;
    const uint32_t k2 = 0x1BD11BDAu ^ k0 ^ k1;   // 0x1BD11BF0
    uint32_t x0 = k0;
    uint32_t x1 = idx + k1;
#define TFR(r) { x0 += x1; x1 = rotl32(x1, (r)); x1 ^= x0; }
    TFR(13) TFR(15) TFR(26) TFR(6)
    x0 += k1; x1 += k2 + 1u;
    TFR(17) TFR(29) TFR(16) TFR(24)
    x0 += k2; x1 += k0 + 2u;
    TFR(13) TFR(15) TFR(26) TFR(6)
    x0 += k0; x1 += k1 + 3u;
    TFR(17) TFR(29) TFR(16) TFR(24)
    x0 += k1; x1 += k2 + 4u;
    TFR(13) TFR(15) TFR(26) TFR(6)
    x0 += k2; x1 += k0 + 5u;
#undef TFR
    return x0 ^ x1;
}

// keep  <=>  uniform(bits) < 0.8f  <=>  bits < 0xCCCCCE00  (exact)
#define KEEP_THRESH 0xCCCCCE00u

// Flash attention + JAX-threefry dropout, split-K.
// Block: 256 threads (4 waves); wave w owns q-rows [blockIdx.x*64 + w*16, +16).
// blockIdx.z selects a K-segment of seg_tiles*64 positions.
// DIRECT=true: single segment, divide and write O. DIRECT=false: write (m,l,O_unnorm) to ws.
template <bool DIRECT>
__global__ void attn_fwd_kernel(const float* __restrict__ Qp,
                                const float* __restrict__ Kp,
                                const float* __restrict__ Vp,
                                const int* __restrict__ isf,
                                float* __restrict__ outp,   // O (DIRECT) or ws
                                int seg_tiles) {
    const int tid  = threadIdx.x;
    const int w    = tid >> 6;
    const int lane = tid & 63;
    const int g    = lane >> 4;   // 16-lane group 0..3
    const int lq   = lane & 15;   // q-column index within wave tile
    const int b    = blockIdx.y;
    const int qwave = blockIdx.x * QBLK + w * 16;

    __shared__ __align__(16) unsigned char smem[24576];
    unsigned char* Kl = smem;                      // K tile bf16 [64][64], swizzled
    unsigned char* Vt = smem + 8192;               // V^T bf16 [d][k], swizzled
    unsigned char* Pl = smem + 16384 + w * 2048;   // per-wave P bf16 [16][64], swizzled

    float fv;
    {
        int iv = isf[0];
        if (iv >= 1 && iv <= (1 << 20)) fv = (float)iv;
        else {
            float f = __int_as_float(iv);
            fv = (f > 1.0e-3f && f < 1.0e6f) ? f : 8.0f;
        }
    }
    const float sc = 1.0f / fv;

    bf16x8 qf[2];
    {
        const float* qp = Qp + (size_t)(b * S_LEN + qwave + lq) * D_DIM + 8 * g;
        #pragma unroll
        for (int h = 0; h < 2; ++h) {
            float4 a = *(const float4*)(qp + 32 * h);
            float4 c = *(const float4*)(qp + 32 * h + 4);
            bf16x8 f;
            f[0] = (short)f2bf(a.x * sc); f[1] = (short)f2bf(a.y * sc);
            f[2] = (short)f2bf(a.z * sc); f[3] = (short)f2bf(a.w * sc);
            f[4] = (short)f2bf(c.x * sc); f[5] = (short)f2bf(c.y * sc);
            f[6] = (short)f2bf(c.z * sc); f[7] = (short)f2bf(c.w * sc);
            qf[h] = f;
        }
    }

    f32x4 acc[4];
    #pragma unroll
    for (int nt = 0; nt < 4; ++nt) { acc[nt][0]=0.f; acc[nt][1]=0.f; acc[nt][2]=0.f; acc[nt][3]=0.f; }
    float mrun = -3.0e38f, lrun = 0.0f;

    const float* Kb = Kp + (size_t)b * S_LEN * D_DIM;
    const float* Vb = Vp + (size_t)b * S_LEN * D_DIM;

    const int kt0 = blockIdx.z * seg_tiles;
    for (int kt = kt0; kt < kt0 + seg_tiles; ++kt) {
        const int kbase = kt * KBLK;
        __syncthreads();

        // ---- stage K tile (bf16, swizzled ^((row&7)<<4))
        #pragma unroll
        for (int i = 0; i < 4; ++i) {
            int p4 = i * 256 + tid;
            int r  = p4 >> 4, c4 = p4 & 15;
            float4 v = *(const float4*)(Kb + (size_t)(kbase + r) * D_DIM + c4 * 4);
            uint2 wv; wv.x = pack2bf(v.x, v.y); wv.y = pack2bf(v.z, v.w);
            *(uint2*)(Kl + ((r * 128 + c4 * 8) ^ ((r & 7) << 4))) = wv;
        }
        // ---- stage V^T (bf16)
        #pragma unroll
        for (int i = 0; i < 2; ++i) {
            int pp = i * 256 + tid;
            int kp = pp >> 4, d4 = (pp & 15) * 4;
            const float* vp = Vb + (size_t)(kbase + 2 * kp) * D_DIM + d4;
            float4 a = *(const float4*)vp;
            float4 c = *(const float4*)(vp + D_DIM);
            *(uint32_t*)(Vt + (((d4 + 0) * 128 + kp * 4) ^ (((d4 + 0) & 7) << 4))) = pack2bf(a.x, c.x);
            *(uint32_t*)(Vt + (((d4 + 1) * 128 + kp * 4) ^ (((d4 + 1) & 7) << 4))) = pack2bf(a.y, c.y);
            *(uint32_t*)(Vt + (((d4 + 2) * 128 + kp * 4) ^ (((d4 + 2) & 7) << 4))) = pack2bf(a.z, c.z);
            *(uint32_t*)(Vt + (((d4 + 3) * 128 + kp * 4) ^ (((d4 + 3) & 7) << 4))) = pack2bf(a.w, c.w);
        }
        __syncthreads();

        // ---- S^T = K_tile @ Q^T
        f32x4 s[4];
        #pragma unroll
        for (int mt = 0; mt < 4; ++mt) { s[mt][0]=0.f; s[mt][1]=0.f; s[mt][2]=0.f; s[mt][3]=0.f; }
        #pragma unroll
        for (int h = 0; h < 2; ++h) {
            #pragma unroll
            for (int mt = 0; mt < 4; ++mt) {
                int r = 16 * mt + lq;
                bf16x8 kf = *(const bf16x8*)(Kl + ((r * 128 + (4 * h + g) * 16) ^ ((r & 7) << 4)));
                s[mt] = __builtin_amdgcn_mfma_f32_16x16x32_bf16(kf, qf[h], s[mt], 0, 0, 0);
            }
        }

        // ---- online softmax (lane-parallel; groups reduced via shfl_xor)
        float tmax = s[0][0];
        #pragma unroll
        for (int mt = 0; mt < 4; ++mt)
            #pragma unroll
            for (int r = 0; r < 4; ++r) tmax = fmaxf(tmax, s[mt][r]);
        tmax = fmaxf(tmax, __shfl_xor(tmax, 16));
        tmax = fmaxf(tmax, __shfl_xor(tmax, 32));
        float mnew = fmaxf(mrun, tmax);
        float pvv[4][4];
        float tsum = 0.f;
        #pragma unroll
        for (int mt = 0; mt < 4; ++mt)
            #pragma unroll
            for (int r = 0; r < 4; ++r) {
                float e = __expf(s[mt][r] - mnew);
                pvv[mt][r] = e; tsum += e;
            }
        tsum += __shfl_xor(tsum, 16);
        tsum += __shfl_xor(tsum, 32);
        float corr = __expf(mrun - mnew);
        lrun = lrun * corr + tsum;   // denominator: pre-dropout
        mrun = mnew;

        // ---- dropout: flat idx = b*2^24 + q*2^12 + k
        const uint32_t cbase = ((uint32_t)b << 24) + ((uint32_t)(qwave + lq) << 12) + (uint32_t)kbase;
        #pragma unroll
        for (int mt = 0; mt < 4; ++mt) {
            float pd[4];
            #pragma unroll
            for (int r = 0; r < 4; ++r) {
                uint32_t bits = threefry_xor(cbase + (uint32_t)(16 * mt + 4 * g + r));
                pd[r] = (bits < KEEP_THRESH) ? pvv[mt][r] : 0.0f;  // 1/0.8 folded later
            }
            uint2 pw; pw.x = pack2bf(pd[0], pd[1]); pw.y = pack2bf(pd[2], pd[3]);
            *(uint2*)(Pl + ((lq * 128 + (16 * mt + 4 * g) * 2) ^ ((lq & 7) << 4))) = pw;
        }

        // TBAA fence: P written as uint2*, read as bf16x8*, same-wave, no barrier.
        asm volatile("" ::: "memory");

        // ---- rescale O accumulator
        float cr0 = __shfl(corr, 4 * g + 0);
        float cr1 = __shfl(corr, 4 * g + 1);
        float cr2 = __shfl(corr, 4 * g + 2);
        float cr3 = __shfl(corr, 4 * g + 3);
        #pragma unroll
        for (int nt = 0; nt < 4; ++nt) {
            acc[nt][0] *= cr0; acc[nt][1] *= cr1; acc[nt][2] *= cr2; acc[nt][3] *= cr3;
        }

        // ---- PV: O += P @ V
        #pragma unroll
        for (int kk = 0; kk < 2; ++kk) {
            bf16x8 pf = *(const bf16x8*)(Pl + ((lq * 128 + kk * 64 + g * 16) ^ ((lq & 7) << 4)));
            #pragma unroll
            for (int nt = 0; nt < 4; ++nt) {
                int d = lq + 16 * nt;
                bf16x8 vf = *(const bf16x8*)(Vt + ((d * 128 + kk * 64 + g * 16) ^ ((d & 7) << 4)));
                acc[nt] = __builtin_amdgcn_mfma_f32_16x16x32_bf16(pf, vf, acc[nt], 0, 0, 0);
            }
        }
    }

    if (DIRECT) {
        // ---- epilogue: O = acc / (l * 0.8)
        float l0 = __shfl(lrun, 4 * g + 0);
        float l1 = __shfl(lrun, 4 * g + 1);
        float l2 = __shfl(lrun, 4 * g + 2);
        float l3 = __shfl(lrun, 4 * g + 3);
        float inv0 = 1.0f / (l0 * 0.8f);
        float inv1 = 1.0f / (l1 * 0.8f);
        float inv2 = 1.0f / (l2 * 0.8f);
        float inv3 = 1.0f / (l3 * 0.8f);
        float* Ob = outp + (size_t)b * S_LEN * D_DIM;
        #pragma unroll
        for (int nt = 0; nt < 4; ++nt) {
            int d = lq + 16 * nt;
            Ob[(size_t)(qwave + 4 * g + 0) * D_DIM + d] = acc[nt][0] * inv0;
            Ob[(size_t)(qwave + 4 * g + 1) * D_DIM + d] = acc[nt][1] * inv1;
            Ob[(size_t)(qwave + 4 * g + 2) * D_DIM + d] = acc[nt][2] * inv2;
            Ob[(size_t)(qwave + 4 * g + 3) * D_DIM + d] = acc[nt][3] * inv3;
        }
    } else {
        // ---- write per-segment partials: [m, l, O_unnorm[64]] per row
        float* seg = outp + (size_t)blockIdx.z * NBATCH * S_LEN * ROWSTRIDE;
        size_t row0 = (size_t)b * S_LEN + qwave;
        if (g == 0) {   // lanes 0-15 hold m,l for rows qwave+lq (uniform across groups)
            float* p = seg + (row0 + lq) * ROWSTRIDE;
            p[0] = mrun; p[1] = lrun;
        }
        #pragma unroll
        for (int nt = 0; nt < 4; ++nt) {
            int d = lq + 16 * nt;
            seg[(row0 + 4 * g + 0) * ROWSTRIDE + 2 + d] = acc[nt][0];
            seg[(row0 + 4 * g + 1) * ROWSTRIDE + 2 + d] = acc[nt][1];
            seg[(row0 + 4 * g + 2) * ROWSTRIDE + 2 + d] = acc[nt][2];
            seg[(row0 + 4 * g + 3) * ROWSTRIDE + 2 + d] = acc[nt][3];
        }
    }
}

// Merge NS segments: O = sum_i e^{m_i-m} O_i / (0.8 * sum_i e^{m_i-m} l_i)
__global__ void combine_kernel(const float* __restrict__ ws, float* __restrict__ Op, int NS) {
    const int tid = threadIdx.x;
    const size_t row = (size_t)blockIdx.x * 4 + (tid >> 6);  // 0 .. B*S_LEN-1
    const int d = tid & 63;
    const size_t SEGF = (size_t)NBATCH * S_LEN * ROWSTRIDE;
    const size_t roff = row * ROWSTRIDE;

    float m = -3.0e38f;
    for (int s = 0; s < NS; ++s) m = fmaxf(m, ws[s * SEGF + roff]);
    float l = 0.f, o = 0.f;
    for (int s = 0; s < NS; ++s) {
        const float* p = ws + s * SEGF + roff;
        float scl = __expf(p[0] - m);
        l += scl * p[1];
        o += scl * p[2 + d];
    }
    Op[row * D_DIM + d] = o / (l * 0.8f);
}

extern "C" void kernel_launch(void* const* d_in, const int* in_sizes, int n_in,
                              void* d_out, int out_size, void* d_ws, size_t ws_size,
                              hipStream_t stream) {
    const float* Q = (const float*)d_in[0];
    const float* K = (const float*)d_in[1];
    const float* V = (const float*)d_in[2];
    const int* isf = (const int*)d_in[3];
    float* O = (float*)d_out;

    const size_t SEGB = (size_t)NBATCH * S_LEN * ROWSTRIDE * sizeof(float);  // 4.33 MB
    int NS = 4;
    while (NS > 1 && ws_size < (size_t)NS * SEGB) NS >>= 1;

    if (NS >= 2) {
        dim3 grid1(S_LEN / QBLK, NBATCH, NS);
        attn_fwd_kernel<false><<<grid1, dim3(256), 0, stream>>>(
            Q, K, V, isf, (float*)d_ws, (S_LEN / KBLK) / NS);
        dim3 grid2((NBATCH * S_LEN) / 4);
        combine_kernel<<<grid2, dim3(256), 0, stream>>>((const float*)d_ws, O, NS);
    } else {
        dim3 grid(S_LEN / QBLK, NBATCH, 1);
        attn_fwd_kernel<true><<<grid, dim3(256), 0, stream>>>(
            Q, K, V, isf, O, S_LEN / KBLK);
    }
}

// Round 9
// 162.239 us; speedup vs baseline: 1.3173x; 1.0615x over previous
//
#include <hip/hip_runtime.h>
#include <stdint.h>

#define S_LEN 4096
#define D_DIM 64
#define KBLK  64
#define QBLK  64
#define NBATCH 4
#define ROWSTRIDE 66   // per-row ws floats: [m2, l, O[64]]  (m2 in log2 domain)

typedef __attribute__((ext_vector_type(8))) short bf16x8;
typedef __attribute__((ext_vector_type(4))) float f32x4;

#define LOG2E 1.4426950408889634f

// v_cvt_pk_bf16_f32: dst.lo = bf16(src0), dst.hi = bf16(src1), RNE (T12/m240)
__device__ __forceinline__ uint32_t pk_bf16(float lo, float hi) {
    uint32_t r;
    asm("v_cvt_pk_bf16_f32 %0, %1, %2" : "=v"(r) : "v"(lo), "v"(hi));
    return r;
}
// rotl as single v_alignbit_b32: alignbit(x,x,s) = rotr(x,s) => rotl(x,n)=alignbit(x,x,32-n)
__device__ __forceinline__ uint32_t rotl32(uint32_t x, int n) {
    return __builtin_amdgcn_alignbit(x, x, 32 - n);
}

// JAX partitionable threefry 32-bit draw, key (0,42): plaintext (0, idx),
// draw = out0 ^ out1. Verified round 6/8 (absmax ~1e-3).
__device__ __forceinline__ uint32_t threefry_xor(uint32_t idx) {
    const uint32_t k0 = 0u, k1 = 42u;
    const uint32_t k2 = 0x1BD11BDAu ^ k0 ^ k1;   // 0x1BD11BF0
    uint32_t x0 = k0;
    uint32_t x1 = idx + k1;
#define TFR(r) { x0 += x1; x1 = rotl32(x1, (r)); x1 ^= x0; }
    TFR(13) TFR(15) TFR(26) TFR(6)
    x0 += k1; x1 += k2 + 1u;
    TFR(17) TFR(29) TFR(16) TFR(24)
    x0 += k2; x1 += k0 + 2u;
    TFR(13) TFR(15) TFR(26) TFR(6)
    x0 += k0; x1 += k1 + 3u;
    TFR(17) TFR(29) TFR(16) TFR(24)
    x0 += k1; x1 += k2 + 4u;
    TFR(13) TFR(15) TFR(26) TFR(6)
    x0 += k2; x1 += k0 + 5u;
#undef TFR
    return x0 ^ x1;
}

// keep  <=>  uniform(bits) < 0.8f  <=>  bits < 0xCCCCCE00  (exact)
#define KEEP_THRESH 0xCCCCCE00u

// Flash attention + JAX-threefry dropout, split-K, log2-domain softmax.
// Block: 256 threads (4 waves); wave w owns q-rows [blockIdx.x*64 + w*16, +16).
// blockIdx.z selects a K-segment of seg_tiles*64 positions.
template <bool DIRECT>
__global__ void attn_fwd_kernel(const float* __restrict__ Qp,
                                const float* __restrict__ Kp,
                                const float* __restrict__ Vp,
                                const int* __restrict__ isf,
                                float* __restrict__ outp,   // O (DIRECT) or ws
                                int seg_tiles) {
    const int tid  = threadIdx.x;
    const int w    = tid >> 6;
    const int lane = tid & 63;
    const int g    = lane >> 4;   // 16-lane group 0..3
    const int lq   = lane & 15;   // q-column index within wave tile
    const int b    = blockIdx.y;
    const int qwave = blockIdx.x * QBLK + w * 16;

    __shared__ __align__(16) unsigned char smem[24576];
    unsigned char* Kl = smem;                      // K tile bf16 [64][64], swizzled
    unsigned char* Vt = smem + 8192;               // V^T bf16 [d][k], swizzled
    unsigned char* Pl = smem + 16384 + w * 2048;   // per-wave P bf16 [16][64], swizzled

    float fv;
    {
        int iv = isf[0];
        if (iv >= 1 && iv <= (1 << 20)) fv = (float)iv;
        else {
            float f = __int_as_float(iv);
            fv = (f > 1.0e-3f && f < 1.0e6f) ? f : 8.0f;
        }
    }
    const float sc = LOG2E / fv;    // fold log2(e): scores land in log2 domain

    bf16x8 qf[2];
    {
        const float* qp = Qp + (size_t)(b * S_LEN + qwave + lq) * D_DIM + 8 * g;
        #pragma unroll
        for (int h = 0; h < 2; ++h) {
            float4 a = *(const float4*)(qp + 32 * h);
            float4 c = *(const float4*)(qp + 32 * h + 4);
            uint32_t w0 = pk_bf16(a.x * sc, a.y * sc);
            uint32_t w1 = pk_bf16(a.z * sc, a.w * sc);
            uint32_t w2 = pk_bf16(c.x * sc, c.y * sc);
            uint32_t w3 = pk_bf16(c.z * sc, c.w * sc);
            bf16x8 f;
            f[0] = (short)(w0 & 0xFFFF); f[1] = (short)(w0 >> 16);
            f[2] = (short)(w1 & 0xFFFF); f[3] = (short)(w1 >> 16);
            f[4] = (short)(w2 & 0xFFFF); f[5] = (short)(w2 >> 16);
            f[6] = (short)(w3 & 0xFFFF); f[7] = (short)(w3 >> 16);
            qf[h] = f;
        }
    }

    f32x4 acc[4];
    #pragma unroll
    for (int nt = 0; nt < 4; ++nt) { acc[nt][0]=0.f; acc[nt][1]=0.f; acc[nt][2]=0.f; acc[nt][3]=0.f; }
    float mrun = -3.0e38f, lrun = 0.0f;   // mrun in log2 units

    const float* Kb = Kp + (size_t)b * S_LEN * D_DIM;
    const float* Vb = Vp + (size_t)b * S_LEN * D_DIM;

    const int kt0 = blockIdx.z * seg_tiles;
    for (int kt = kt0; kt < kt0 + seg_tiles; ++kt) {
        const int kbase = kt * KBLK;
        __syncthreads();

        // ---- stage K tile (bf16, swizzled ^((row&7)<<4))
        #pragma unroll
        for (int i = 0; i < 4; ++i) {
            int p4 = i * 256 + tid;
            int r  = p4 >> 4, c4 = p4 & 15;
            float4 v = *(const float4*)(Kb + (size_t)(kbase + r) * D_DIM + c4 * 4);
            uint2 wv; wv.x = pk_bf16(v.x, v.y); wv.y = pk_bf16(v.z, v.w);
            *(uint2*)(Kl + ((r * 128 + c4 * 8) ^ ((r & 7) << 4))) = wv;
        }
        // ---- stage V^T (bf16)
        #pragma unroll
        for (int i = 0; i < 2; ++i) {
            int pp = i * 256 + tid;
            int kp = pp >> 4, d4 = (pp & 15) * 4;
            const float* vp = Vb + (size_t)(kbase + 2 * kp) * D_DIM + d4;
            float4 a = *(const float4*)vp;
            float4 c = *(const float4*)(vp + D_DIM);
            *(uint32_t*)(Vt + (((d4 + 0) * 128 + kp * 4) ^ (((d4 + 0) & 7) << 4))) = pk_bf16(a.x, c.x);
            *(uint32_t*)(Vt + (((d4 + 1) * 128 + kp * 4) ^ (((d4 + 1) & 7) << 4))) = pk_bf16(a.y, c.y);
            *(uint32_t*)(Vt + (((d4 + 2) * 128 + kp * 4) ^ (((d4 + 2) & 7) << 4))) = pk_bf16(a.z, c.z);
            *(uint32_t*)(Vt + (((d4 + 3) * 128 + kp * 4) ^ (((d4 + 3) & 7) << 4))) = pk_bf16(a.w, c.w);
        }
        __syncthreads();

        // ---- S^T = K_tile @ Q^T  (scores already × log2e)
        f32x4 s[4];
        #pragma unroll
        for (int mt = 0; mt < 4; ++mt) { s[mt][0]=0.f; s[mt][1]=0.f; s[mt][2]=0.f; s[mt][3]=0.f; }
        #pragma unroll
        for (int h = 0; h < 2; ++h) {
            #pragma unroll
            for (int mt = 0; mt < 4; ++mt) {
                int r = 16 * mt + lq;
                bf16x8 kf = *(const bf16x8*)(Kl + ((r * 128 + (4 * h + g) * 16) ^ ((r & 7) << 4)));
                s[mt] = __builtin_amdgcn_mfma_f32_16x16x32_bf16(kf, qf[h], s[mt], 0, 0, 0);
            }
        }

        // ---- online softmax in log2 domain (lane-parallel; group-reduce via shfl_xor)
        float tmax = s[0][0];
        #pragma unroll
        for (int mt = 0; mt < 4; ++mt)
            #pragma unroll
            for (int r = 0; r < 4; ++r) tmax = fmaxf(tmax, s[mt][r]);
        tmax = fmaxf(tmax, __shfl_xor(tmax, 16));
        tmax = fmaxf(tmax, __shfl_xor(tmax, 32));
        float mnew = fmaxf(mrun, tmax);
        float pvv[4][4];
        float tsum = 0.f;
        #pragma unroll
        for (int mt = 0; mt < 4; ++mt)
            #pragma unroll
            for (int r = 0; r < 4; ++r) {
                float e = __builtin_amdgcn_exp2f(s[mt][r] - mnew);
                pvv[mt][r] = e; tsum += e;
            }
        tsum += __shfl_xor(tsum, 16);
        tsum += __shfl_xor(tsum, 32);
        float corr = __builtin_amdgcn_exp2f(mrun - mnew);
        lrun = lrun * corr + tsum;   // denominator: pre-dropout
        mrun = mnew;

        // ---- dropout: flat idx = b*2^24 + q*2^12 + k
        const uint32_t cbase = ((uint32_t)b << 24) + ((uint32_t)(qwave + lq) << 12) + (uint32_t)kbase;
        #pragma unroll
        for (int mt = 0; mt < 4; ++mt) {
            float pd[4];
            #pragma unroll
            for (int r = 0; r < 4; ++r) {
                uint32_t bits = threefry_xor(cbase + (uint32_t)(16 * mt + 4 * g + r));
                pd[r] = (bits < KEEP_THRESH) ? pvv[mt][r] : 0.0f;  // 1/0.8 folded later
            }
            uint2 pw; pw.x = pk_bf16(pd[0], pd[1]); pw.y = pk_bf16(pd[2], pd[3]);
            *(uint2*)(Pl + ((lq * 128 + (16 * mt + 4 * g) * 2) ^ ((lq & 7) << 4))) = pw;
        }

        // TBAA fence: P written as uint2*, read as bf16x8*, same-wave, no barrier.
        asm volatile("" ::: "memory");

        // ---- rescale O accumulator
        float cr0 = __shfl(corr, 4 * g + 0);
        float cr1 = __shfl(corr, 4 * g + 1);
        float cr2 = __shfl(corr, 4 * g + 2);
        float cr3 = __shfl(corr, 4 * g + 3);
        #pragma unroll
        for (int nt = 0; nt < 4; ++nt) {
            acc[nt][0] *= cr0; acc[nt][1] *= cr1; acc[nt][2] *= cr2; acc[nt][3] *= cr3;
        }

        // ---- PV: O += P @ V
        #pragma unroll
        for (int kk = 0; kk < 2; ++kk) {
            bf16x8 pf = *(const bf16x8*)(Pl + ((lq * 128 + kk * 64 + g * 16) ^ ((lq & 7) << 4)));
            #pragma unroll
            for (int nt = 0; nt < 4; ++nt) {
                int d = lq + 16 * nt;
                bf16x8 vf = *(const bf16x8*)(Vt + ((d * 128 + kk * 64 + g * 16) ^ ((d & 7) << 4)));
                acc[nt] = __builtin_amdgcn_mfma_f32_16x16x32_bf16(pf, vf, acc[nt], 0, 0, 0);
            }
        }
    }

    if (DIRECT) {
        // ---- epilogue: O = acc / (l * 0.8)
        float l0 = __shfl(lrun, 4 * g + 0);
        float l1 = __shfl(lrun, 4 * g + 1);
        float l2 = __shfl(lrun, 4 * g + 2);
        float l3 = __shfl(lrun, 4 * g + 3);
        float inv0 = 1.0f / (l0 * 0.8f);
        float inv1 = 1.0f / (l1 * 0.8f);
        float inv2 = 1.0f / (l2 * 0.8f);
        float inv3 = 1.0f / (l3 * 0.8f);
        float* Ob = outp + (size_t)b * S_LEN * D_DIM;
        #pragma unroll
        for (int nt = 0; nt < 4; ++nt) {
            int d = lq + 16 * nt;
            Ob[(size_t)(qwave + 4 * g + 0) * D_DIM + d] = acc[nt][0] * inv0;
            Ob[(size_t)(qwave + 4 * g + 1) * D_DIM + d] = acc[nt][1] * inv1;
            Ob[(size_t)(qwave + 4 * g + 2) * D_DIM + d] = acc[nt][2] * inv2;
            Ob[(size_t)(qwave + 4 * g + 3) * D_DIM + d] = acc[nt][3] * inv3;
        }
    } else {
        // ---- write per-segment partials: [m2, l, O_unnorm[64]] per row
        float* seg = outp + (size_t)blockIdx.z * NBATCH * S_LEN * ROWSTRIDE;
        size_t row0 = (size_t)b * S_LEN + qwave;
        if (g == 0) {   // lanes 0-15 hold m,l for rows qwave+lq (uniform across groups)
            float* p = seg + (row0 + lq) * ROWSTRIDE;
            p[0] = mrun; p[1] = lrun;
        }
        #pragma unroll
        for (int nt = 0; nt < 4; ++nt) {
            int d = lq + 16 * nt;
            seg[(row0 + 4 * g + 0) * ROWSTRIDE + 2 + d] = acc[nt][0];
            seg[(row0 + 4 * g + 1) * ROWSTRIDE + 2 + d] = acc[nt][1];
            seg[(row0 + 4 * g + 2) * ROWSTRIDE + 2 + d] = acc[nt][2];
            seg[(row0 + 4 * g + 3) * ROWSTRIDE + 2 + d] = acc[nt][3];
        }
    }
}

// Merge NS segments (log2-domain m): O = sum_i 2^{m_i-m} O_i / (0.8 * sum_i 2^{m_i-m} l_i)
__global__ void combine_kernel(const float* __restrict__ ws, float* __restrict__ Op, int NS) {
    const int tid = threadIdx.x;
    const size_t row = (size_t)blockIdx.x * 4 + (tid >> 6);  // 0 .. B*S_LEN-1
    const int d = tid & 63;
    const size_t SEGF = (size_t)NBATCH * S_LEN * ROWSTRIDE;
    const size_t roff = row * ROWSTRIDE;

    float m = -3.0e38f;
    for (int s = 0; s < NS; ++s) m = fmaxf(m, ws[s * SEGF + roff]);
    float l = 0.f, o = 0.f;
    for (int s = 0; s < NS; ++s) {
        const float* p = ws + s * SEGF + roff;
        float scl = __builtin_amdgcn_exp2f(p[0] - m);
        l += scl * p[1];
        o += scl * p[2 + d];
    }
    Op[row * D_DIM + d] = o / (l * 0.8f);
}

extern "C" void kernel_launch(void* const* d_in, const int* in_sizes, int n_in,
                              void* d_out, int out_size, void* d_ws, size_t ws_size,
                              hipStream_t stream) {
    const float* Q = (const float*)d_in[0];
    const float* K = (const float*)d_in[1];
    const float* V = (const float*)d_in[2];
    const int* isf = (const int*)d_in[3];
    float* O = (float*)d_out;

    const size_t SEGB = (size_t)NBATCH * S_LEN * ROWSTRIDE * sizeof(float);  // 4.33 MB
    int NS = 8;                                  // 2048 blocks: up to 6 blk/CU (LDS-capped)
    while (NS > 1 && ws_size < (size_t)NS * SEGB) NS >>= 1;

    if (NS >= 2) {
        dim3 grid1(S_LEN / QBLK, NBATCH, NS);
        attn_fwd_kernel<false><<<grid1, dim3(256), 0, stream>>>(
            Q, K, V, isf, (float*)d_ws, (S_LEN / KBLK) / NS);
        dim3 grid2((NBATCH * S_LEN) / 4);
        combine_kernel<<<grid2, dim3(256), 0, stream>>>((const float*)d_ws, O, NS);
    } else {
        dim3 grid(S_LEN / QBLK, NBATCH, 1);
        attn_fwd_kernel<true><<<grid, dim3(256), 0, stream>>>(
            Q, K, V, isf, O, S_LEN / KBLK);
    }
}